// Round 6
// baseline (89.777 us; speedup 1.0000x reference)
//
#include <hip/hip_runtime.h>

#define RH 128
#define RW 128
#define CS 21    // src channels
#define IH 512
#define IW 512
#define NPIX (RH * RW)
#define NP 13        // dy groups = waves per bilateral block
#define SPITCH 160   // padded src row pitch (floats): 12 zero | 128 | 20 zero
#define SCH (RH * SPITCH)   // per-channel plane stride = 20480
#define IPITCH 152   // padded im row pitch (float4): 12 reflect | 128 | 12 reflect

// ---------------- K1a-H: horizontal antialiased downsample 512x512x21 -> tmpH[512][160][21] ----------------
// c-fastest mapping; pad columns written as zero (propagate through vertical pass).
__global__ void ds_src_h_kernel(const float* __restrict__ in, float* __restrict__ tmpH) {
    int idx = blockIdx.x * blockDim.x + threadIdx.x;
    if (idx >= IH * SPITCH * CS) return;
    int c = idx % CS;
    int t = idx / CS;
    int xp = t % SPITCH;
    int y = t / SPITCH;                 // input row 0..511
    int x = xp - 12;
    if (x < 0 || x >= RW) { tmpH[idx] = 0.f; return; }

    float sx = 4.f * x + 1.5f;
    float wx[8]; int jx[8]; float wxs = 0.f;
#pragma unroll
    for (int k = 0; k < 8; ++k) {
        int j = 4 * x - 2 + k;
        float w = 1.f - fabsf(sx - (float)j) * 0.25f;
        if (j < 0 || j >= IW) { w = 0.f; j = 0; }
        jx[k] = j; wx[k] = w; wxs += w;
    }
    const float* row = in + (size_t)y * IW * CS + c;
    float s = 0.f;
#pragma unroll
    for (int b = 0; b < 8; ++b) s += wx[b] * row[jx[b] * CS];
    tmpH[idx] = s / wxs;
}

// ---------------- K1a-V: vertical pass tmpH -> planar zero-padded srcP[21][128][160] ----------------
__global__ void ds_src_v_kernel(const float* __restrict__ tmpH, float* __restrict__ srcP) {
    int idx = blockIdx.x * blockDim.x + threadIdx.x;
    if (idx >= RH * SPITCH * CS) return;
    int c = idx % CS;
    int t = idx / CS;
    int xp = t % SPITCH;
    int y = t / SPITCH;                 // output row 0..127

    float sy = 4.f * y + 1.5f;
    float wy[8]; int jy[8]; float wys = 0.f;
#pragma unroll
    for (int k = 0; k < 8; ++k) {
        int j = 4 * y - 2 + k;
        float w = 1.f - fabsf(sy - (float)j) * 0.25f;
        if (j < 0 || j >= IH) { w = 0.f; j = 0; }
        jy[k] = j; wy[k] = w; wys += w;
    }
    float s = 0.f;
#pragma unroll
    for (int a = 0; a < 8; ++a)
        s += wy[a] * tmpH[((size_t)jy[a] * SPITCH + xp) * CS + c];
    srcP[(size_t)c * SCH + y * SPITCH + xp] = s / wys;
}

// ---------------- K1b: downsample im 512->128, float4, horizontally reflect-padded ----------------
__global__ void downsample_im_kernel(const float* __restrict__ in, float4* __restrict__ out) {
    int idx = blockIdx.x * blockDim.x + threadIdx.x;
    if (idx >= RH * IPITCH) return;
    int xp = idx % IPITCH;
    int y = idx / IPITCH;
    int gx = xp - 12;
    gx = gx < 0 ? -gx : (gx > RW - 1 ? 2 * (RW - 1) - gx : gx);

    float wy[8], wx[8];
    int jy[8], jx[8];
    float sy = 4.f * y + 1.5f, sx = 4.f * gx + 1.5f;
    float wys = 0.f, wxs = 0.f;
#pragma unroll
    for (int k = 0; k < 8; ++k) {
        int j = 4 * y - 2 + k;
        float w = 1.f - fabsf(sy - (float)j) * 0.25f;
        if (j < 0 || j >= IH) { w = 0.f; j = 0; }
        jy[k] = j; wy[k] = w; wys += w;
        int j2 = 4 * gx - 2 + k;
        float w2 = 1.f - fabsf(sx - (float)j2) * 0.25f;
        if (j2 < 0 || j2 >= IW) { w2 = 0.f; j2 = 0; }
        jx[k] = j2; wx[k] = w2; wxs += w2;
    }
    float inv = 1.f / (wys * wxs);
    float s0 = 0.f, s1 = 0.f, s2 = 0.f;
#pragma unroll
    for (int a = 0; a < 8; ++a) {
        const float* row = in + (size_t)(jy[a] * IW) * 3;
        float r0 = 0.f, r1 = 0.f, r2 = 0.f;
#pragma unroll
        for (int b = 0; b < 8; ++b) {
            const float* pp = row + jx[b] * 3;
            r0 += wx[b] * pp[0];
            r1 += wx[b] * pp[1];
            r2 += wx[b] * pp[2];
        }
        s0 += wy[a] * r0; s1 += wy[a] * r1; s2 += wy[a] * r2;
    }
    out[idx] = make_float4(s0 * inv, s1 * inv, s2 * inv, 0.f);
}

// ---------------- K2: fused joint bilateral + 13-way reduce ----------------
// Block = 13 waves (832 thr) = the 13 dy-groups of one 64-pixel half-row.
// Wave p handles dy in {p, p+13} (in-range); LDS deterministic reduce; write out_r.
#define BKT (NP * 64)   // 832
__global__ __launch_bounds__(BKT) void bilateral_kernel(
        const float* __restrict__ srcP,   // [21][128][160] zero-padded
        const float4* __restrict__ im4P,  // [128][152] reflect-padded
        float* __restrict__ outr) {       // [NPIX][21] interleaved
    __shared__ float red[NP][CS * 64];

    int tid = threadIdx.x;
    int p = tid >> 6;                     // 0..12
    int lane = tid & 63;
    int y = blockIdx.x >> 1;
    int xbase = (blockIdx.x & 1) << 6;
    int x = xbase + lane;

    float4 ctr = im4P[y * IPITCH + x + 12];
    float acc[CS];
#pragma unroll
    for (int c = 0; c < CS; ++c) acc[c] = 0.f;

#pragma unroll
    for (int rep = 0; rep < 2; ++rep) {
        int dy = p + rep * NP;
        if (dy < 25) {
            int ry = y + dy - 12;
            if (ry >= 0 && ry < RH) {     // wave-uniform; src zero-pad handles x
                float fdy = (float)(dy - 12);
                float gy = fdy * fdy;
                const float* srow = srcP + ry * SPITCH + x;     // + c*SCH + dx
                const float4* irow = im4P + ry * IPITCH + x;    // + dx
#pragma unroll 5
                for (int dx = 0; dx < 25; ++dx) {
                    float4 q = irow[dx];
                    float d0 = q.x - ctr.x, d1 = q.y - ctr.y, d2 = q.z - ctr.z;
                    float fdx = (float)(dx - 12);
                    float e = -(d0 * d0 + d1 * d1 + d2 * d2) * (1.f / 18.f)
                              - (gy + fdx * fdx) * (1.f / 128.f);
                    float cw = __expf(e);
#pragma unroll
                    for (int c = 0; c < CS; ++c)
                        acc[c] = fmaf(cw, srow[c * SCH + dx], acc[c]);
                }
            }
        }
    }

#pragma unroll
    for (int c = 0; c < CS; ++c) red[p][c * 64 + lane] = acc[c];
    __syncthreads();

    for (int q = tid; q < CS * 64; q += BKT) {
        float s = 0.f;
#pragma unroll
        for (int pp = 0; pp < NP; ++pp) s += red[pp][q];
        int c = q >> 6;
        int px = q & 63;
        int pix = (y << 7) + xbase + px;
        outr[(size_t)pix * CS + c] = s;
    }
}

// ---------------- K3: bilinear upsample 128 -> 512 ----------------
__global__ void upsample_kernel(const float* __restrict__ inr, float* __restrict__ out, int total) {
    int idx = blockIdx.x * blockDim.x + threadIdx.x;
    if (idx >= total) return;
    int c = idx % CS;
    int t = idx / CS;
    int X = t % IW, Y = t / IW;
    float fy = 0.25f * (float)Y - 0.375f;
    float fx = 0.25f * (float)X - 0.375f;
    int y0 = (int)floorf(fy); float ty = fy - (float)y0;
    int x0 = (int)floorf(fx); float tx = fx - (float)x0;
    int y1 = y0 + 1, x1 = x0 + 1;
    y0 = min(max(y0, 0), RH - 1); y1 = min(max(y1, 0), RH - 1);
    x0 = min(max(x0, 0), RW - 1); x1 = min(max(x1, 0), RW - 1);
    float v00 = inr[(y0 * RW + x0) * CS + c], v01 = inr[(y0 * RW + x1) * CS + c];
    float v10 = inr[(y1 * RW + x0) * CS + c], v11 = inr[(y1 * RW + x1) * CS + c];
    float v0 = v00 + tx * (v01 - v00);
    float v1 = v10 + tx * (v11 - v10);
    out[idx] = v0 + ty * (v1 - v0);
}

extern "C" void kernel_launch(void* const* d_in, const int* in_sizes, int n_in,
                              void* d_out, int out_size, void* d_ws, size_t ws_size,
                              hipStream_t stream) {
    const float* src = (const float*)d_in[0];   // (1,512,512,21) f32
    const float* im  = (const float*)d_in[1];   // (1,512,512,3)  f32
    float* out = (float*)d_out;                 // (1,512,512,21) f32 = 22,020,096 B
    char* ws = (char*)d_ws;

    // scratch in d_out (fully overwritten by K3 at the end, stream-ordered):
    float* tmpH = out;                                  // [512][160][21] = 6,881,280 B
    float* srcP = (float*)((char*)d_out + 20299776);    // [21][128][160] = 1,720,320 B (tail, exact fit)
    // small scratch in ws (1,687,552 B total):
    float4* im4P = (float4*)(ws);                       // [128][152]     =   311,296 B
    float* out_r = (float*)(ws + 311296);               // [128][128][21] = 1,376,256 B

    int th = IH * SPITCH * CS;
    ds_src_h_kernel<<<(th + 255) / 256, 256, 0, stream>>>(src, tmpH);
    int tv = RH * SPITCH * CS;
    ds_src_v_kernel<<<(tv + 255) / 256, 256, 0, stream>>>(tmpH, srcP);
    int t2 = RH * IPITCH;
    downsample_im_kernel<<<(t2 + 255) / 256, 256, 0, stream>>>(im, im4P);

    // 256 blocks x 13 waves = one block per CU
    bilateral_kernel<<<256, BKT, 0, stream>>>(srcP, im4P, out_r);

    int t3 = IH * IW * CS;
    upsample_kernel<<<(t3 + 255) / 256, 256, 0, stream>>>(out_r, out, t3);
}